// Round 9
// baseline (121.272 us; speedup 1.0000x reference)
//
#include <hip/hip_runtime.h>

#define HW_    12544   // 112*112
#define W_     112
#define NP_    4096    // planes = 32*128
#define OHW_   3136
#define OW_    56
#define HPLANE (112*56)

typedef float f32x4 __attribute__((ext_vector_type(4)));

__device__ __forceinline__ unsigned bf16rn(float a) {
    unsigned u = __float_as_uint(a);
    return (u + 0x7FFFu + ((u >> 16) & 1u)) >> 16;
}
__device__ __forceinline__ unsigned pack2(float lo, float hi) {
    return bf16rn(lo) | (bf16rn(hi) << 16);
}

// ---------------- Pass 1: streaming h-blur (both dc, bf16) + phase sums ----------------
// grid 12544 x 256. task g = (plane bc, row r, 16-col seg s). 6 contiguous
// NONTEMPORAL float4 loads (input never re-read; keep L3 for hb), static-index
// h extraction, 2x uint4 stores (cached - vblur re-reads). 392 blocks/batch exact.
__global__ __launch_bounds__(256) void hsum(const float* __restrict__ inp,
                                            ushort* __restrict__ hb,
                                            float* __restrict__ part) {
    const int g   = blockIdx.x * 256 + threadIdx.x;   // exactly 4096*784
    const int bc  = g / 784;
    const int rem = g - bc * 784;
    const int r   = rem / 7;
    const int s   = rem - r * 7;

    const int base4 = (s == 0) ? 0 : ((s == 6) ? 22 : 4 * s - 1);
    const f32x4* rp = (const f32x4*)(inp + (size_t)bc * HW_ + r * W_) + base4;
    const f32x4 v0 = __builtin_nontemporal_load(rp + 0);
    const f32x4 v1 = __builtin_nontemporal_load(rp + 1);
    const f32x4 v2 = __builtin_nontemporal_load(rp + 2);
    const f32x4 v3 = __builtin_nontemporal_load(rp + 3);
    const f32x4 v4 = __builtin_nontemporal_load(rp + 4);
    const f32x4 v5 = __builtin_nontemporal_load(rp + 5);
    const float x[24] = {v0.x,v0.y,v0.z,v0.w, v1.x,v1.y,v1.z,v1.w,
                         v2.x,v2.y,v2.z,v2.w, v3.x,v3.y,v3.z,v3.w,
                         v4.x,v4.y,v4.z,v4.w, v5.x,v5.y,v5.z,v5.w};

    float h0[8], h1[8], se = 0.f, so = 0.f;
    if (s == 0) {                                   // x = cols 0..23, owns 0..15
#pragma unroll
        for (int m = 0; m < 16; m += 2) { se += x[m]*x[m]; so += x[m+1]*x[m+1]; }
        h0[0] = 3.f*x[0] + 4.f*x[1] + x[2];         // reflect col -1 -> 1
#pragma unroll
        for (int u = 1; u < 8; ++u)
            h0[u] = (x[2*u-1] + x[2*u+2]) + 3.f*(x[2*u] + x[2*u+1]);
#pragma unroll
        for (int u = 0; u < 8; ++u)
            h1[u] = (x[2*u] + x[2*u+3]) + 3.f*(x[2*u+1] + x[2*u+2]);
    } else if (s == 6) {                            // x = cols 88..111, owns 96..111
#pragma unroll
        for (int m = 8; m < 24; m += 2) { se += x[m]*x[m]; so += x[m+1]*x[m+1]; }
#pragma unroll
        for (int u = 0; u < 7; ++u)
            h0[u] = (x[7+2*u] + x[10+2*u]) + 3.f*(x[8+2*u] + x[9+2*u]);
        h0[7] = x[21] + 4.f*x[22] + 3.f*x[23];      // reflect cols 112/113
#pragma unroll
        for (int u = 0; u < 7; ++u)
            h1[u] = (x[8+2*u] + x[11+2*u]) + 3.f*(x[9+2*u] + x[10+2*u]);
        h1[7] = h0[7];
    } else {                                        // x = cols 16s-4..16s+19, owns 16s..16s+15
#pragma unroll
        for (int m = 0; m < 16; m += 2) { se += x[m+4]*x[m+4]; so += x[m+5]*x[m+5]; }
#pragma unroll
        for (int u = 0; u < 8; ++u) {
            h0[u] = (x[2*u+3] + x[2*u+6]) + 3.f*(x[2*u+4] + x[2*u+5]);
            h1[u] = (x[2*u+4] + x[2*u+7]) + 3.f*(x[2*u+5] + x[2*u+6]);
        }
    }

    const uint4 o0 = make_uint4(pack2(h0[0],h0[1]), pack2(h0[2],h0[3]),
                                pack2(h0[4],h0[5]), pack2(h0[6],h0[7]));
    const uint4 o1 = make_uint4(pack2(h1[0],h1[1]), pack2(h1[2],h1[3]),
                                pack2(h1[4],h1[5]), pack2(h1[6],h1[7]));
    *(uint4*)(hb + (size_t)bc * HPLANE + r * 56 + 8 * s) = o0;
    *(uint4*)(hb + (size_t)(NP_ + bc) * HPLANE + r * 56 + 8 * s) = o1;

    // phase partials: phase = (r&1) + 2*(col&1)
    const int rpar = r & 1;
    float s0 = rpar ? 0.f : se, s1 = rpar ? se : 0.f;
    float s2 = rpar ? 0.f : so, s3 = rpar ? so : 0.f;
    for (int off = 32; off > 0; off >>= 1) {
        s0 += __shfl_down(s0, off); s1 += __shfl_down(s1, off);
        s2 += __shfl_down(s2, off); s3 += __shfl_down(s3, off);
    }
    __shared__ float ws[4][4];
    const int tid = threadIdx.x;
    if ((tid & 63) == 0) {
        const int w = tid >> 6;
        ws[w][0] = s0; ws[w][1] = s1; ws[w][2] = s2; ws[w][3] = s3;
    }
    __syncthreads();
    if (tid < 4)
        part[blockIdx.x * 4 + tid] = ws[0][tid] + ws[1][tid] + ws[2][tid] + ws[3][tid];
}

// ---------------- Pass 1.5: argmax over 392 block-partials per batch ----------------
__global__ __launch_bounds__(512) void finalize_idx(const float* __restrict__ part,
                                                    int* __restrict__ pidx) {
    const int t = threadIdx.x;              // 512 = 32 b x 4 c x 4 p
    const int p = t & 3, c = (t >> 2) & 3, b = t >> 4;
    const float* pp = part + ((size_t)b * 392 + c * 98) * 4 + p;
    float v = 0.f;
    for (int i = 0; i < 98; ++i) v += pp[i * 4];
    v += __shfl_down(v, 8);                 // combine c pairs
    v += __shfl_down(v, 4);
    const int lane = t & 63;
    const int base = lane & ~15;            // this batch's lane group (c==0, p=0..3)
    const float w0 = __shfl(v, base + 0), w1 = __shfl(v, base + 1);
    const float w2 = __shfl(v, base + 2), w3 = __shfl(v, base + 3);
    if (p == 0 && c == 0) {
        int idx = 0; float best = w0;
        if (w1 > best) { best = w1; idx = 1; }
        if (w2 > best) { best = w2; idx = 2; }
        if (w3 > best) { best = w3; idx = 3; }
        pidx[b] = idx;
    }
}

// ---------------- Pass 2: v-blur of selected-dc bf16 h, select dr ----------------
__global__ __launch_bounds__(256) void vblur(const ushort* __restrict__ hb,
                                             const int* __restrict__ pidx,
                                             float* __restrict__ out) {
    const int g  = blockIdx.x * 256 + threadIdx.x;   // exactly 4096*392
    const int bc = g / 392;
    const int rr = g - bc * 392;
    const int oh = rr / 7;
    const int s  = rr - oh * 7;
    const int ph = pidx[bc >> 7];
    const int dr = ph & 1, dc = ph >> 1;
    const uint4* H = (const uint4*)(hb + ((size_t)(dc ? NP_ + bc : bc)) * HPLANE);
    const int jb = 2 * oh + dr - 1;

    uint4 w[4];
#pragma unroll
    for (int k = 0; k < 4; ++k) {
        int j = jb + k;
        int aj = j < 0 ? -j : j;
        j = aj < 222 - aj ? aj : 222 - aj;
        w[k] = H[j * 7 + s];
    }

    float acc[8];
#pragma unroll
    for (int k = 0; k < 4; ++k) {
        const unsigned a = w[k].x, b = w[k].y, c = w[k].z, d = w[k].w;
        float y[8];
        y[0] = __uint_as_float(a << 16); y[1] = __uint_as_float(a & 0xFFFF0000u);
        y[2] = __uint_as_float(b << 16); y[3] = __uint_as_float(b & 0xFFFF0000u);
        y[4] = __uint_as_float(c << 16); y[5] = __uint_as_float(c & 0xFFFF0000u);
        y[6] = __uint_as_float(d << 16); y[7] = __uint_as_float(d & 0xFFFF0000u);
        const float wk = (k == 1 || k == 2) ? 3.f : 1.f;
        if (k == 0) {
#pragma unroll
            for (int u = 0; u < 8; ++u) acc[u] = y[u];
        } else {
#pragma unroll
            for (int u = 0; u < 8; ++u) acc[u] = fmaf(wk, y[u], acc[u]);
        }
    }

    float* o = out + (size_t)bc * OHW_ + oh * OW_ + 8 * s;
    const f32x4 r0 = {acc[0] * 0.015625f, acc[1] * 0.015625f,
                      acc[2] * 0.015625f, acc[3] * 0.015625f};
    const f32x4 r1 = {acc[4] * 0.015625f, acc[5] * 0.015625f,
                      acc[6] * 0.015625f, acc[7] * 0.015625f};
    __builtin_nontemporal_store(r0, (f32x4*)o);
    __builtin_nontemporal_store(r1, (f32x4*)(o + 4));
}

extern "C" void kernel_launch(void* const* d_in, const int* in_sizes, int n_in,
                              void* d_out, int out_size, void* d_ws, size_t ws_size,
                              hipStream_t stream) {
    const float* inp = (const float*)d_in[0];
    ushort* hb  = (ushort*)d_ws;                            // 2*4096*112*56*2 = 102,760,448 B
    float* part = (float*)((char*)d_ws + 102760448);        // 12544*4 floats = 200,704 B
    int*  pidx  = (int*)((char*)d_ws + 102760448 + 200704); // 32 ints
    hsum<<<12544, 256, 0, stream>>>(inp, hb, part);
    finalize_idx<<<1, 512, 0, stream>>>(part, pidx);
    vblur<<<6272, 256, 0, stream>>>(hb, pidx, (float*)d_out);
}

// Round 10
// 85.846 us; speedup vs baseline: 1.4127x; 1.4127x over previous
//
#include <hip/hip_runtime.h>

#define HW_    12544   // 112*112
#define W_     112
#define NP_    4096    // planes = 32*128
#define OHW_   3136
#define OW_    56
#define HPLANE (112*56)

__device__ __forceinline__ unsigned bf16rn(float a) {
    unsigned u = __float_as_uint(a);
    return (u + 0x7FFFu + ((u >> 16) & 1u)) >> 16;
}
__device__ __forceinline__ unsigned pack2(float lo, float hi) {
    return bf16rn(lo) | (bf16rn(hi) << 16);
}

// ---------------- Pass 1: streaming h-blur (both dc, bf16) + phase sums ----------------
// grid 12544 x 256. task g = (plane bc, row r, 16-col seg s). 6 contiguous float4
// loads, static-index h extraction, 2x uint4 stores. 392 blocks per batch (exact).
// (Identical to the proven 86.3 us R7 kernel.)
__global__ __launch_bounds__(256) void hsum(const float* __restrict__ inp,
                                            ushort* __restrict__ hb,
                                            float* __restrict__ part) {
    const int g   = blockIdx.x * 256 + threadIdx.x;   // exactly 4096*784
    const int bc  = g / 784;
    const int rem = g - bc * 784;
    const int r   = rem / 7;
    const int s   = rem - r * 7;

    const int base4 = (s == 0) ? 0 : ((s == 6) ? 22 : 4 * s - 1);
    const float4* rp = (const float4*)(inp + (size_t)bc * HW_ + r * W_) + base4;
    const float4 v0 = rp[0], v1 = rp[1], v2 = rp[2];
    const float4 v3 = rp[3], v4 = rp[4], v5 = rp[5];
    const float x[24] = {v0.x,v0.y,v0.z,v0.w, v1.x,v1.y,v1.z,v1.w,
                         v2.x,v2.y,v2.z,v2.w, v3.x,v3.y,v3.z,v3.w,
                         v4.x,v4.y,v4.z,v4.w, v5.x,v5.y,v5.z,v5.w};

    float h0[8], h1[8], se = 0.f, so = 0.f;
    if (s == 0) {                                   // x = cols 0..23, owns 0..15
#pragma unroll
        for (int m = 0; m < 16; m += 2) { se += x[m]*x[m]; so += x[m+1]*x[m+1]; }
        h0[0] = 3.f*x[0] + 4.f*x[1] + x[2];         // reflect col -1 -> 1
#pragma unroll
        for (int u = 1; u < 8; ++u)
            h0[u] = (x[2*u-1] + x[2*u+2]) + 3.f*(x[2*u] + x[2*u+1]);
#pragma unroll
        for (int u = 0; u < 8; ++u)
            h1[u] = (x[2*u] + x[2*u+3]) + 3.f*(x[2*u+1] + x[2*u+2]);
    } else if (s == 6) {                            // x = cols 88..111, owns 96..111
#pragma unroll
        for (int m = 8; m < 24; m += 2) { se += x[m]*x[m]; so += x[m+1]*x[m+1]; }
#pragma unroll
        for (int u = 0; u < 7; ++u)
            h0[u] = (x[7+2*u] + x[10+2*u]) + 3.f*(x[8+2*u] + x[9+2*u]);
        h0[7] = x[21] + 4.f*x[22] + 3.f*x[23];      // reflect cols 112/113
#pragma unroll
        for (int u = 0; u < 7; ++u)
            h1[u] = (x[8+2*u] + x[11+2*u]) + 3.f*(x[9+2*u] + x[10+2*u]);
        h1[7] = h0[7];
    } else {                                        // x = cols 16s-4..16s+19, owns 16s..16s+15
#pragma unroll
        for (int m = 0; m < 16; m += 2) { se += x[m+4]*x[m+4]; so += x[m+5]*x[m+5]; }
#pragma unroll
        for (int u = 0; u < 8; ++u) {
            h0[u] = (x[2*u+3] + x[2*u+6]) + 3.f*(x[2*u+4] + x[2*u+5]);
            h1[u] = (x[2*u+4] + x[2*u+7]) + 3.f*(x[2*u+5] + x[2*u+6]);
        }
    }

    const uint4 o0 = make_uint4(pack2(h0[0],h0[1]), pack2(h0[2],h0[3]),
                                pack2(h0[4],h0[5]), pack2(h0[6],h0[7]));
    const uint4 o1 = make_uint4(pack2(h1[0],h1[1]), pack2(h1[2],h1[3]),
                                pack2(h1[4],h1[5]), pack2(h1[6],h1[7]));
    *(uint4*)(hb + (size_t)bc * HPLANE + r * 56 + 8 * s) = o0;
    *(uint4*)(hb + (size_t)(NP_ + bc) * HPLANE + r * 56 + 8 * s) = o1;

    // phase partials: phase = (r&1) + 2*(col&1)
    const int rpar = r & 1;
    float s0 = rpar ? 0.f : se, s1 = rpar ? se : 0.f;
    float s2 = rpar ? 0.f : so, s3 = rpar ? so : 0.f;
    for (int off = 32; off > 0; off >>= 1) {
        s0 += __shfl_down(s0, off); s1 += __shfl_down(s1, off);
        s2 += __shfl_down(s2, off); s3 += __shfl_down(s3, off);
    }
    __shared__ float ws[4][4];
    const int tid = threadIdx.x;
    if ((tid & 63) == 0) {
        const int w = tid >> 6;
        ws[w][0] = s0; ws[w][1] = s1; ws[w][2] = s2; ws[w][3] = s3;
    }
    __syncthreads();
    if (tid < 4)
        part[blockIdx.x * 4 + tid] = ws[0][tid] + ws[1][tid] + ws[2][tid] + ws[3][tid];
}

// ---------------- Pass 2: fused argmax + v-blur of selected-dc bf16 h ----------------
// 6272 blocks = exactly 196 per batch -> each block is single-batch. Block start:
// 4 waves reduce the batch's 392x4 partials (deterministic tree), argmax in-reg.
__global__ __launch_bounds__(256) void vblur(const ushort* __restrict__ hb,
                                             const float* __restrict__ part,
                                             float* __restrict__ out) {
    __shared__ float s4[4];
    const int tid = threadIdx.x;
    const int b = blockIdx.x / 196;                  // batch (exact)
    {
        const int w = tid >> 6, lane = tid & 63;     // wave w reduces phase w
        const float* pp = part + (size_t)b * 392 * 4 + w;
        float v = 0.f;
#pragma unroll
        for (int i = 0; i < 7; ++i) {
            const int idx = lane + i * 64;
            if (idx < 392) v += pp[idx * 4];
        }
        for (int off = 32; off > 0; off >>= 1) v += __shfl_down(v, off);
        if (lane == 0) s4[w] = v;
    }
    __syncthreads();
    const float n0 = s4[0], n1 = s4[1], n2 = s4[2], n3 = s4[3];
    int ph = 0; float best = n0;
    if (n1 > best) { best = n1; ph = 1; }
    if (n2 > best) { best = n2; ph = 2; }
    if (n3 > best) { best = n3; ph = 3; }
    const int dr = ph & 1, dc = ph >> 1;

    const int g  = blockIdx.x * 256 + tid;           // exactly 4096*392
    const int bc = g / 392;
    const int rr = g - bc * 392;
    const int oh = rr / 7;
    const int s  = rr - oh * 7;
    const uint4* H = (const uint4*)(hb + ((size_t)(dc ? NP_ + bc : bc)) * HPLANE);
    const int jb = 2 * oh + dr - 1;

    uint4 w4[4];
#pragma unroll
    for (int k = 0; k < 4; ++k) {
        int j = jb + k;
        int aj = j < 0 ? -j : j;
        j = aj < 222 - aj ? aj : 222 - aj;
        w4[k] = H[j * 7 + s];
    }

    float acc[8];
#pragma unroll
    for (int k = 0; k < 4; ++k) {
        const unsigned a = w4[k].x, b2 = w4[k].y, c = w4[k].z, d = w4[k].w;
        float y[8];
        y[0] = __uint_as_float(a << 16);  y[1] = __uint_as_float(a & 0xFFFF0000u);
        y[2] = __uint_as_float(b2 << 16); y[3] = __uint_as_float(b2 & 0xFFFF0000u);
        y[4] = __uint_as_float(c << 16);  y[5] = __uint_as_float(c & 0xFFFF0000u);
        y[6] = __uint_as_float(d << 16);  y[7] = __uint_as_float(d & 0xFFFF0000u);
        const float wk = (k == 1 || k == 2) ? 3.f : 1.f;
        if (k == 0) {
#pragma unroll
            for (int u = 0; u < 8; ++u) acc[u] = y[u];
        } else {
#pragma unroll
            for (int u = 0; u < 8; ++u) acc[u] = fmaf(wk, y[u], acc[u]);
        }
    }

    float* o = out + (size_t)bc * OHW_ + oh * OW_ + 8 * s;
    *(float4*)o = make_float4(acc[0] * 0.015625f, acc[1] * 0.015625f,
                              acc[2] * 0.015625f, acc[3] * 0.015625f);
    *(float4*)(o + 4) = make_float4(acc[4] * 0.015625f, acc[5] * 0.015625f,
                                    acc[6] * 0.015625f, acc[7] * 0.015625f);
}

extern "C" void kernel_launch(void* const* d_in, const int* in_sizes, int n_in,
                              void* d_out, int out_size, void* d_ws, size_t ws_size,
                              hipStream_t stream) {
    const float* inp = (const float*)d_in[0];
    ushort* hb  = (ushort*)d_ws;                            // 2*4096*112*56*2 = 102,760,448 B
    float* part = (float*)((char*)d_ws + 102760448);        // 12544*4 floats = 200,704 B
    hsum<<<12544, 256, 0, stream>>>(inp, hb, part);
    vblur<<<6272, 256, 0, stream>>>(hb, part, (float*)d_out);
}